// Round 12
// baseline (76.433 us; speedup 1.0000x reference)
//
#include <hip/hip_runtime.h>
#include <math.h>

#define B_ 512
#define C_ 100000
#define D_ 128
#define CT 128
#define NBLK ((C_ + CT - 1) / CT)   // 782 tiles
#define G_ NBLK
#define NSTEP (NBLK * 2)            // 1564 (tile, row-half) steps
#define MAIN_GRID 512
#define TILE_BYTES 32768            // 128 cols x 128 bf16 (norm pre-folded)
#define LOG2E 1.4426950408889634f
#define K2S (2.0f * LOG2E)          // score_log2 = dot*K2S + K18S
#define K18S (-18.0f * LOG2E)
#define NPAIR_P (C_ / 2)            // 50000 proxy row-pairs
#define NPAIR_T (NPAIR_P + B_ / 2)  // + 256 batch row-pairs
#define CONV_BLOCKS 2048
#define PRAW_BYTES ((size_t)C_ * D_ * 4)   // 51,200,000

typedef __attribute__((ext_vector_type(8))) short short8;  // 8 bf16 (MFMA A/B frag)
typedef __attribute__((ext_vector_type(4))) float f32x4;   // MFMA C/D frag

__device__ __forceinline__ unsigned short f2b(float x) {  // RNE f32->bf16
  union { float f; unsigned int i; } v; v.f = x;
  unsigned int r = v.i + 0x7FFFu + ((v.i >> 16) & 1u);
  return (unsigned short)(r >> 16);
}
__device__ __forceinline__ float b2f(unsigned short u) {
  union { float f; unsigned int i; } v; v.i = ((unsigned int)u) << 16; return v.f;
}

#if defined(__has_builtin)
#if __has_builtin(__builtin_amdgcn_exp2f)
#define EXP2F(x) __builtin_amdgcn_exp2f(x)
#endif
#endif
#ifndef EXP2F
#define EXP2F(x) __expf(0.69314718055994531f * (x))
#endif

// async global -> LDS, 16 B per lane; LDS dest = wave-uniform base + lane*16
__device__ __forceinline__ void gll16(const void* g, void* l) {
  __builtin_amdgcn_global_load_lds(
      (const __attribute__((address_space(1))) void*)g,
      (__attribute__((address_space(3))) void*)l, 16, 0, 0);
}

// --- kernel 1: streaming normalize+convert (pcopy -> swizzled tiles, batch -> xnb)
// Identical to R7's converter except it reads the ws COPY of praw (A/B probe).
__global__ __launch_bounds__(256) void convert_kernel(
    const float* __restrict__ pcopy, const float* __restrict__ batch,
    unsigned char* __restrict__ pb, unsigned short* __restrict__ xnb)
{
  // zero the 96 tail cols of tile 781 (units 512..2047 -> bytes 8192..32767)
  int gid = blockIdx.x * 256 + threadIdx.x;
  if (gid < 3072) {
    ushort4 z = {0, 0, 0, 0};
    *(ushort4*)(pb + (size_t)(NBLK - 1) * TILE_BYTES + 8192 + gid * 8) = z;
  }
  const int lane = threadIdx.x & 63;
  const int wv   = threadIdx.x >> 6;
  const int f    = lane & 31;        // float4 index within the 512B row
  const int rh   = lane >> 5;        // which row of the pair
  const int nw   = CONV_BLOCKS * 4;
  for (int p = blockIdx.x * 4 + wv; p < NPAIR_T; p += nw) {
    const bool isp = (p < NPAIR_P);
    const int row = isp ? (p * 2 + rh) : ((p - NPAIR_P) * 2 + rh);
    const float4* src = isp ? (const float4*)pcopy : (const float4*)batch;
    float4 v = src[(size_t)row * 32 + f];
    float ss = v.x * v.x + v.y * v.y + v.z * v.z + v.w * v.w;
    ss += __shfl_xor(ss, 1);
    ss += __shfl_xor(ss, 2);
    ss += __shfl_xor(ss, 4);
    ss += __shfl_xor(ss, 8);
    ss += __shfl_xor(ss, 16);
    float sc = 3.0f * __frsqrt_rn(fmaxf(ss, 1e-24f));   // 3/||row|| (0 row -> 0)
    ushort4 o;
    o.x = f2b(v.x * sc); o.y = f2b(v.y * sc);
    o.z = f2b(v.z * sc); o.w = f2b(v.w * sc);
    if (isp) {
      int t = row >> 7, tcol = row & 127;
      int unit = tcol * 16 + ((f >> 1) ^ (tcol & 7));   // swizzled 16B slot
      *(ushort4*)(pb + (size_t)t * TILE_BYTES + unit * 16 + (f & 1) * 8) = o;
    } else {
      *(ushort4*)((unsigned char*)xnb + (size_t)row * 256 + f * 8) = o;
    }
  }
}

// --- kernel 2: persistent pipelined main (R7-proven, ~16us) --------------------
__global__ __launch_bounds__(512, 4) void pnca_main_kernel(
    const unsigned char* __restrict__ pb, const unsigned short* __restrict__ xnb,
    float* __restrict__ pt)
{
  __shared__ __align__(16) unsigned char lds[2][TILE_BYTES];

  const int tid  = threadIdx.x;
  const int lane = tid & 63;
  const int w    = tid >> 6;
  const int ll   = lane & 15;
  const int lq   = lane >> 4;

  int s = blockIdx.x;
  const int half  = s & 1;
  const int rbase = half * 256 + w * 32;

  // A fragments: this wave's 32 rows of xnb (L2-hot), constant across steps
  short8 a[2][4];
#pragma unroll
  for (int m = 0; m < 2; ++m)
#pragma unroll
    for (int ks = 0; ks < 4; ++ks)
      a[m][ks] = *(const short8*)(xnb + (size_t)(rbase + m * 16 + ll) * D_ + ks * 32 + lq * 8);
  asm volatile("s_waitcnt vmcnt(0)" ::: "memory");   // A-loads retired: vmcnt tracks gll16 only

  // prologue: stage step s into buf 0 (4 gll16 per thread -> 32KB per block)
  {
    const unsigned char* tp = pb + (size_t)(s >> 1) * TILE_BYTES;
#pragma unroll
    for (int k = 0; k < 4; ++k)
      gll16(tp + (size_t)((w * 4 + k) * 64 + lane) * 16, &lds[0][(w * 4 + k) * 1024]);
  }

  int p = 0;
  while (true) {
    const int snext = s + MAIN_GRID;
    const bool hasnext = (snext < NSTEP);
    if (hasnext) {
      const unsigned char* tp = pb + (size_t)(snext >> 1) * TILE_BYTES;
#pragma unroll
      for (int k = 0; k < 4; ++k)
        gll16(tp + (size_t)((w * 4 + k) * 64 + lane) * 16, &lds[p ^ 1][(w * 4 + k) * 1024]);
      asm volatile("s_waitcnt vmcnt(4)" ::: "memory");  // buf[p] done; next 4 in flight
    } else {
      asm volatile("s_waitcnt vmcnt(0)" ::: "memory");
    }
    __builtin_amdgcn_s_barrier();
    __builtin_amdgcn_sched_barrier(0);

    const unsigned char* buf = lds[p];
    float part[2][4] = {{0.f, 0.f, 0.f, 0.f}, {0.f, 0.f, 0.f, 0.f}};
#pragma unroll
    for (int g = 0; g < 8; ++g) {
      const int colg = g * 16 + ll;
      short8 bfr[4];
#pragma unroll
      for (int ks = 0; ks < 4; ++ks)
        bfr[ks] = *(const short8*)(buf + (size_t)(colg * 16 + ((ks * 4 + lq) ^ (colg & 7))) * 16);
      f32x4 acc0 = (f32x4){0.f, 0.f, 0.f, 0.f};
      f32x4 acc1 = (f32x4){0.f, 0.f, 0.f, 0.f};
#pragma unroll
      for (int ks = 0; ks < 4; ++ks) {
        acc0 = __builtin_amdgcn_mfma_f32_16x16x32_bf16(a[0][ks], bfr[ks], acc0, 0, 0, 0);
        acc1 = __builtin_amdgcn_mfma_f32_16x16x32_bf16(a[1][ks], bfr[ks], acc1, 0, 0, 0);
      }
#pragma unroll
      for (int r = 0; r < 4; ++r) {
        part[0][r] += EXP2F(fmaf(acc0[r], K2S, K18S));
        part[1][r] += EXP2F(fmaf(acc1[r], K2S, K18S));
      }
    }
    // 16-lane reduce, write partials; C/D layout: col=ll, row=lq*4+r
#pragma unroll
    for (int m = 0; m < 2; ++m)
#pragma unroll
      for (int r = 0; r < 4; ++r) {
        float v = part[m][r];
        v += __shfl_xor(v, 1);
        v += __shfl_xor(v, 2);
        v += __shfl_xor(v, 4);
        v += __shfl_xor(v, 8);
        if (ll == 0)
          pt[(size_t)(s >> 1) * B_ + rbase + m * 16 + lq * 4 + r] = v;
      }
    __builtin_amdgcn_s_barrier();   // buf[p] reads done before it is re-staged
    if (!hasnext) break;
    s = snext;
    p ^= 1;
  }
}

// --- kernel 3: per-row combine + positive distance + loss ---------------------
__global__ __launch_bounds__(256) void finalize_rows_kernel(
    const float* __restrict__ praw, const unsigned short* __restrict__ xnb,
    const int* __restrict__ labels, const float* __restrict__ pt,
    float* __restrict__ lossb)
{
  int lane = threadIdx.x & 63, wv = threadIdx.x >> 6;
  int row = blockIdx.x * 4 + wv;             // grid=128 -> 512 rows
  int lab = labels[row];
  float2 pv = *(const float2*)(praw + (size_t)lab * D_ + lane * 2);
  ushort2 xv = *(const ushort2*)(xnb + (size_t)row * D_ + lane * 2);
  float xa = b2f(xv.x), xb = b2f(xv.y);
  float ssp = pv.x * pv.x + pv.y * pv.y;
  float dp  = xa * pv.x + xb * pv.y;
#pragma unroll
  for (int off = 32; off; off >>= 1) {
    ssp += __shfl_xor(ssp, off);
    dp  += __shfl_xor(dp, off);
  }
  float pd = 18.f - 2.f * dp * (3.f / fmaxf(sqrtf(ssp), 1e-12f));  // positive dist
  float s = 0.f;
  for (int gg = lane; gg < G_; gg += 64) s += pt[(size_t)gg * B_ + row];
#pragma unroll
  for (int off = 32; off; off >>= 1) s += __shfl_xor(s, off);
  if (lane == 0) {
    const float tail = 96.0f * EXP2F(K18S);   // zero-filled OOB cols' exact sum
    lossb[row] = pd + logf(s - __expf(-pd) - tail);
  }
}

// --- kernel 4: mean over 512 rows ---------------------------------------------
__global__ __launch_bounds__(512) void reduce_mean_kernel(
    const float* __restrict__ lossb, float* __restrict__ out)
{
  int t = threadIdx.x;
  float v = lossb[t];
#pragma unroll
  for (int off = 1; off < 64; off <<= 1) v += __shfl_xor(v, off);
  __shared__ float red[8];
  if ((t & 63) == 0) red[t >> 6] = v;
  __syncthreads();
  if (t == 0) {
    float tot = 0.f;
    for (int i = 0; i < 8; ++i) tot += red[i];
    out[0] = tot / (float)B_;
  }
}

extern "C" void kernel_launch(void* const* d_in, const int* in_sizes, int n_in,
                              void* d_out, int out_size, void* d_ws, size_t ws_size,
                              hipStream_t stream)
{
  const float* batch   = (const float*)d_in[0];
  const int*   labels  = (const int*)d_in[1];
  const float* proxies = (const float*)d_in[2];
  float* out = (float*)d_out;

  unsigned char* ws = (unsigned char*)d_ws;
  float*          pcopy = (float*)ws;                                 // 51.2 MB
  unsigned short* xnb   = (unsigned short*)(ws + PRAW_BYTES);         // 128 KB
  unsigned char*  pb    = ws + PRAW_BYTES + 131072;                   // 25.6 MB
  float* pt    = (float*)(ws + PRAW_BYTES + 131072 + (size_t)NBLK * TILE_BYTES);
  float* lossb = (float*)(ws + PRAW_BYTES + 131072 + (size_t)NBLK * TILE_BYTES
                          + (size_t)G_ * B_ * 4);

  // ingest probe: the runtime's optimized D2D path moves praw into fast ws memory
  hipMemcpyAsync(pcopy, proxies, PRAW_BYTES, hipMemcpyDeviceToDevice, stream);

  convert_kernel<<<CONV_BLOCKS, 256, 0, stream>>>(pcopy, batch, pb, xnb);
  pnca_main_kernel<<<MAIN_GRID, 512, 0, stream>>>(pb, xnb, pt);
  finalize_rows_kernel<<<B_ / 4, 256, 0, stream>>>(proxies, xnb, labels, pt, lossb);
  reduce_mean_kernel<<<1, 512, 0, stream>>>(lossb, out);
}

// Round 13
// 39.877 us; speedup vs baseline: 1.9167x; 1.9167x over previous
//
#include <hip/hip_runtime.h>
#include <hip/hip_bf16.h>
#include <math.h>

#define B_ 512
#define C_ 100000
#define D_ 128
#define SC 64                          // proxy cols per step
#define NSTEP ((C_ + SC - 1) / SC)     // 1563 steps
#define NPAD (NSTEP * SC - C_)         // 32 zero-padded cols
#define GRID_MAIN 256                  // persistent, 1 block/CU
#define LOG2E 1.4426950408889634f
#define K2S (2.0f * LOG2E)             // score_log2 = dot*K2S + K18S
#define K18S (-18.0f * LOG2E)

typedef __attribute__((ext_vector_type(8))) short short8;  // 8 bf16 (MFMA A/B frag)
typedef __attribute__((ext_vector_type(4))) float f32x4;   // MFMA C/D frag

__device__ __forceinline__ unsigned short f2b(float x) {  // RNE f32->bf16
  union { float f; unsigned int i; } v; v.f = x;
  unsigned int r = v.i + 0x7FFFu + ((v.i >> 16) & 1u);
  return (unsigned short)(r >> 16);
}
__device__ __forceinline__ float b2f(unsigned short u) {
  union { float f; unsigned int i; } v; v.i = ((unsigned int)u) << 16; return v.f;
}

#if defined(__has_builtin)
#if __has_builtin(__builtin_amdgcn_exp2f)
#define EXP2F(x) __builtin_amdgcn_exp2f(x)
#endif
#endif
#ifndef EXP2F
#define EXP2F(x) __expf(0.69314718055994531f * (x))
#endif

// async global -> LDS, 16 B per lane; LDS dest = wave-uniform base, HW adds lane*16
__device__ __forceinline__ void gll16(const void* g, void* l) {
  __builtin_amdgcn_global_load_lds(
      (const __attribute__((address_space(1))) void*)g,
      (__attribute__((address_space(3))) void*)l, 16, 0, 0);
}

// --- kernel A: normalize batch rows to norm 3, store bf16 ---------------------
__global__ __launch_bounds__(256) void batch_norm_kernel(
    const float* __restrict__ batch, unsigned short* __restrict__ xnb)
{
  int lane = threadIdx.x & 63, wv = threadIdx.x >> 6;
  int r = blockIdx.x * 4 + wv;               // grid=128 -> 512 rows
  float2 v = *(const float2*)(batch + (size_t)r * D_ + lane * 2);
  float ss = v.x * v.x + v.y * v.y;
#pragma unroll
  for (int off = 32; off; off >>= 1) ss += __shfl_xor(ss, off);
  float sc = 3.f / fmaxf(sqrtf(ss), 1e-12f);
  ushort2 o; o.x = f2b(v.x * sc); o.y = f2b(v.y * sc);
  *(ushort2*)(xnb + (size_t)r * D_ + lane * 2) = o;
}

// --- fused persistent main ----------------------------------------------------
// 256 blocks x 512 thr (8 waves); block b owns steps st = b, b+256, ...
// Per step (64 proxy cols): gll16-stage raw f32 (F dbuf) || MFMA+exp from bf16
// (B dbuf) -> sync -> cooperative convert F->B (once!, norm folded) -> sync.
// part[4][4] accumulates across ALL steps; one pt write per block at the end.
__global__ __launch_bounds__(512, 2) void pnca_main_kernel(
    const float* __restrict__ praw, const unsigned short* __restrict__ xnb,
    float* __restrict__ pt)
{
  __shared__ __align__(16) float         fbuf[2][SC * D_];       // 2 x 32 KB f32
  __shared__ __align__(16) unsigned char bbuf[2][SC * D_ * 2];   // 2 x 16 KB bf16 (swizzled)

  const int tid  = threadIdx.x;
  const int lane = tid & 63;
  const int w    = tid >> 6;
  const int ll   = lane & 15;
  const int lq   = lane >> 4;
  const int st0  = blockIdx.x;

  // A fragments: wave w owns batch rows w*64 .. w*64+63 (xnb L2-hot), loaded once
  short8 a[4][4];
#pragma unroll
  for (int m = 0; m < 4; ++m)
#pragma unroll
    for (int ks = 0; ks < 4; ++ks)
      a[m][ks] = *(const short8*)(xnb + (size_t)(w * 64 + m * 16 + ll) * D_ + ks * 32 + lq * 8);

  float part[4][4];
#pragma unroll
  for (int m = 0; m < 4; ++m)
#pragma unroll
    for (int r = 0; r < 4; ++r) part[m][r] = 0.f;

  // stage step st's 64 cols x 512B of raw f32 into fbuf[pp] (linear, 4 gll16/thread)
  auto STAGE = [&](int st, int pp) {
    const unsigned char* gb = (const unsigned char*)praw;
#pragma unroll
    for (int k = 0; k < 4; ++k) {
      int slot = k * 512 + tid;                 // 16B unit index within the tile
      int gr   = st * SC + (slot >> 5);         // proxy row
      if (gr >= C_) gr = C_ - 1;
      gll16(gb + ((size_t)gr * 32 + (slot & 31)) * 16,
            (unsigned char*)fbuf[pp] + (size_t)(k * 512 + w * 64) * 16);
    }
  };

  // cooperative convert: 8 threads per col; norm folded into bf16; swizzled B
  auto CVT = [&](int st, int pp) {
    const int c = tid >> 3, j = tid & 7;
    const float* Fb = fbuf[pp] + (size_t)c * D_;
    float x[16]; float ss = 0.f;
#pragma unroll
    for (int i = 0; i < 4; ++i) {
      float4 v = *(const float4*)(Fb + (j + 8 * i) * 4);
      x[4*i+0] = v.x; x[4*i+1] = v.y; x[4*i+2] = v.z; x[4*i+3] = v.w;
      ss += v.x * v.x + v.y * v.y + v.z * v.z + v.w * v.w;
    }
    ss += __shfl_xor(ss, 1);
    ss += __shfl_xor(ss, 2);
    ss += __shfl_xor(ss, 4);
    float sc = (st * SC + c < C_) ? 3.0f * __frsqrt_rn(fmaxf(ss, 1e-24f)) : 0.0f;
    unsigned char* Bb = bbuf[pp];
#pragma unroll
    for (int i = 0; i < 4; ++i) {
      union { unsigned long long q; __hip_bfloat162 h[2]; } u2;
      u2.h[0] = __float22bfloat162_rn(make_float2(x[4*i]   * sc, x[4*i+1] * sc));
      u2.h[1] = __float22bfloat162_rn(make_float2(x[4*i+2] * sc, x[4*i+3] * sc));
      int lu = (j >> 1) + 4 * i;                // logical 16B unit (dims 4j+32i..)
      int pu = lu ^ (c & 7);                    // XOR swizzle
      *(unsigned long long*)(Bb + ((size_t)c * 16 + pu) * 16 + (j & 1) * 8) = u2.q;
    }
  };

  auto COMPUTE = [&](int pp) {
    const unsigned char* Bb = bbuf[pp];
#pragma unroll
    for (int g = 0; g < 4; ++g) {
      const int cg = g * 16 + ll;
      short8 bfr[4];
#pragma unroll
      for (int ks = 0; ks < 4; ++ks)
        bfr[ks] = *(const short8*)(Bb + (size_t)(cg * 16 + ((ks * 4 + lq) ^ (cg & 7))) * 16);
      f32x4 acc[4];
#pragma unroll
      for (int m = 0; m < 4; ++m) acc[m] = (f32x4){0.f, 0.f, 0.f, 0.f};
#pragma unroll
      for (int ks = 0; ks < 4; ++ks)
#pragma unroll
        for (int m = 0; m < 4; ++m)
          acc[m] = __builtin_amdgcn_mfma_f32_16x16x32_bf16(a[m][ks], bfr[ks], acc[m], 0, 0, 0);
#pragma unroll
      for (int m = 0; m < 4; ++m)
#pragma unroll
        for (int r = 0; r < 4; ++r)
          part[m][r] += EXP2F(fmaf(acc[m][r], K2S, K18S));
    }
  };

  // prologue: stage + convert first step
  STAGE(st0, 0);
  __syncthreads();          // drains vmcnt(0): F0 complete
  CVT(st0, 0);
  __syncthreads();          // B0 ready

  int p = 0;
  for (int st = st0; st < NSTEP; st += GRID_MAIN) {
    const int stn = st + GRID_MAIN;
    const bool hn = (stn < NSTEP);            // block-uniform
    if (hn) STAGE(stn, p ^ 1);                // next f32 tile in flight
    COMPUTE(p);                                // hides gll16 latency
    __syncthreads();                           // vmcnt(0)+lgkm: F[p^1] staged
    if (hn) CVT(stn, p ^ 1);
    __syncthreads();                           // B[p^1] ready
    p ^= 1;
  }

  // epilogue: 16-lane reduce of per-lane partial sums, one write per row
#pragma unroll
  for (int m = 0; m < 4; ++m)
#pragma unroll
    for (int r = 0; r < 4; ++r) {
      float v = part[m][r];
      v += __shfl_xor(v, 1);
      v += __shfl_xor(v, 2);
      v += __shfl_xor(v, 4);
      v += __shfl_xor(v, 8);
      if (ll == 0)
        pt[(size_t)blockIdx.x * B_ + w * 64 + m * 16 + lq * 4 + r] = v;
    }
}

// --- kernel 3: per-row combine + positive distance + loss ---------------------
__global__ __launch_bounds__(256) void finalize_rows_kernel(
    const float* __restrict__ praw, const unsigned short* __restrict__ xnb,
    const int* __restrict__ labels, const float* __restrict__ pt,
    float* __restrict__ lossb)
{
  int lane = threadIdx.x & 63, wv = threadIdx.x >> 6;
  int row = blockIdx.x * 4 + wv;             // grid=128 -> 512 rows
  int lab = labels[row];
  float2 pv = *(const float2*)(praw + (size_t)lab * D_ + lane * 2);
  ushort2 xv = *(const ushort2*)(xnb + (size_t)row * D_ + lane * 2);
  float xa = b2f(xv.x), xb = b2f(xv.y);
  float ssp = pv.x * pv.x + pv.y * pv.y;
  float dp  = xa * pv.x + xb * pv.y;
#pragma unroll
  for (int off = 32; off; off >>= 1) {
    ssp += __shfl_xor(ssp, off);
    dp  += __shfl_xor(dp, off);
  }
  float pd = 18.f - 2.f * dp * (3.f / fmaxf(sqrtf(ssp), 1e-12f));  // positive dist
  float s = 0.f;
#pragma unroll
  for (int gg = 0; gg < GRID_MAIN / 64; ++gg)
    s += pt[(size_t)(gg * 64 + lane) * B_ + row];
#pragma unroll
  for (int off = 32; off; off >>= 1) s += __shfl_xor(s, off);
  if (lane == 0) {
    const float tail = (float)NPAD * EXP2F(K18S);   // zero-padded cols' exact sum
    lossb[row] = pd + logf(s - __expf(-pd) - tail);
  }
}

// --- kernel 4: mean over 512 rows ---------------------------------------------
__global__ __launch_bounds__(512) void reduce_mean_kernel(
    const float* __restrict__ lossb, float* __restrict__ out)
{
  int t = threadIdx.x;
  float v = lossb[t];
#pragma unroll
  for (int off = 1; off < 64; off <<= 1) v += __shfl_xor(v, off);
  __shared__ float red[8];
  if ((t & 63) == 0) red[t >> 6] = v;
  __syncthreads();
  if (t == 0) {
    float tot = 0.f;
    for (int i = 0; i < 8; ++i) tot += red[i];
    out[0] = tot / (float)B_;
  }
}

extern "C" void kernel_launch(void* const* d_in, const int* in_sizes, int n_in,
                              void* d_out, int out_size, void* d_ws, size_t ws_size,
                              hipStream_t stream)
{
  const float* batch   = (const float*)d_in[0];
  const int*   labels  = (const int*)d_in[1];
  const float* proxies = (const float*)d_in[2];
  float* out = (float*)d_out;

  unsigned char* ws = (unsigned char*)d_ws;
  unsigned short* xnb = (unsigned short*)ws;                   // 128 KB
  float* pt    = (float*)(ws + 131072);                        // 256*512*4 = 512 KB
  float* lossb = (float*)(ws + 131072 + (size_t)GRID_MAIN * B_ * 4);  // 2 KB

  batch_norm_kernel<<<B_ / 4, 256, 0, stream>>>(batch, xnb);
  pnca_main_kernel<<<GRID_MAIN, 512, 0, stream>>>(proxies, xnb, pt);
  finalize_rows_kernel<<<B_ / 4, 256, 0, stream>>>(proxies, xnb, labels, pt, lossb);
  reduce_mean_kernel<<<1, 512, 0, stream>>>(lossb, out);
}